// Round 10
// baseline (553.586 us; speedup 1.0000x reference)
//
#include <hip/hip_runtime.h>

#define NV 400000
#define KOFF 27
#define CD 64
#define DD 128
#define HH 128
#define WW 128
#define TABN (2*DD*HH*WW)
#define EPSV 1e-5f

typedef _Float16 f16;
typedef _Float16 f16x8 __attribute__((ext_vector_type(8)));
typedef float f32x16 __attribute__((ext_vector_type(16)));

// ---- workspace layout (bytes) ----
#define OFF_NBR   0ull
#define OFF_X1    43200000ull
#define OFF_X2    94400000ull
#define OFF_TAB   94400000ull     // table dead before x2 written
#define OFF_HIST  111177216ull    // 64K cells * 4B, inside x2 region (dead pre-conv2)
#define OFF_FS    111439360ull    // sorted feats, 1.6MB, inside x2 region (dead pre-conv2)
#define OFF_W2T   145600000ull
#define OFF_W3T   145821184ull
#define OFF_ZERO  146042368ull

#define GLDS16(gp, lp) __builtin_amdgcn_global_load_lds( \
    (__attribute__((address_space(1))) void*)(gp), \
    (__attribute__((address_space(3))) void*)(lp), 16, 0, 0)

// cell = (b, z/4, y/4, x/4) -> 2*32*32*32 = 65536 spatial buckets
__device__ __forceinline__ int cell_of(int4 c) {
    return ((c.x * 32 + (c.y >> 2)) * 32 + (c.z >> 2)) * 32 + (c.w >> 2);
}

// ---- init: table=-1; hist=0; weights -> f16 chunk-major wTg[k][cin/8][cout][cin&7]
__global__ void k_init(const float* __restrict__ w2, const float* __restrict__ w3,
                       int* __restrict__ tab, f16* __restrict__ w2t,
                       f16* __restrict__ w3t, f16* __restrict__ zrow,
                       int* __restrict__ hist) {
    int t = blockIdx.x * 256 + threadIdx.x;           // grid: 4096*256
    int4* tv = (int4*)tab;
    if (t < TABN / 4) tv[t] = make_int4(-1, -1, -1, -1);
    if (t < 65536) hist[t] = 0;
    if (t < KOFF * CD * CD) {
        int k = t >> 12, r = t & 4095, c = r >> 6, ci = r & 63;
        int d = (k << 12) + ((ci >> 3) << 9) + (c << 3) + (ci & 7);
        w2t[d] = (f16)w2[(k << 12) + (ci << 6) + c];
        w3t[d] = (f16)w3[(k << 12) + (ci << 6) + c];
    }
    if (t < CD) zrow[t] = (f16)0.f;
}

// ---- spatial counting-sort: hist -> scan -> rank assignment ----
__global__ void k_hist(const int4* __restrict__ coords, int* __restrict__ hist) {
    int i = blockIdx.x * 256 + threadIdx.x;
    if (i >= NV) return;
    atomicAdd(&hist[cell_of(coords[i])], 1);
}

// exclusive prefix sum over 65536 ints, single workgroup of 1024 threads
__global__ __launch_bounds__(1024) void k_scan(int* __restrict__ hist) {
    __shared__ int part[1024];
    int t = threadIdx.x;
    int base = t * 64;
    int s = 0;
    #pragma unroll
    for (int j = 0; j < 64; j++) s += hist[base + j];
    part[t] = s;
    __syncthreads();
    for (int off = 1; off < 1024; off <<= 1) {
        int v = (t >= off) ? part[t - off] : 0;
        __syncthreads();
        part[t] += v;
        __syncthreads();
    }
    int ex = (t == 0) ? 0 : part[t - 1];
    #pragma unroll
    for (int j = 0; j < 64; j++) {
        int h = hist[base + j];
        hist[base + j] = ex;
        ex += h;
    }
}

// rank r = cell-contiguous position. Writes:
//   tab[site] = r        (neighbor table in RANK space)
//   nbr[13*NV + r] = i   (k=13 is always self -> slot stores ORIG index:
//                         the scatter-back permutation, zero extra memory)
//   feats_s[r] = feats[i] (sorted features for layer 1)
__global__ void k_rank(const int4* __restrict__ coords, const float* __restrict__ feats,
                       int* __restrict__ hist, int* __restrict__ tab,
                       int* __restrict__ nbr, float* __restrict__ feats_s) {
    int i = blockIdx.x * 256 + threadIdx.x;
    if (i >= NV) return;
    int4 c = coords[i];
    int r = atomicAdd(&hist[cell_of(c)], 1);
    int flat = ((c.x * DD + c.y) * HH + c.z) * WW + c.w;
    tab[flat] = r;
    nbr[13 * (size_t)NV + r] = i;
    feats_s[r] = feats[i];
}

// neighbor rulebook in rank space; iterates SORTED order (local tab reads).
// k=13 skipped (slot holds orig index).
__global__ void k_nbr2(const int4* __restrict__ coords, const int* __restrict__ tab,
                       int* __restrict__ nbr) {
    int r = blockIdx.x * 256 + threadIdx.x;
    if (r >= NV) return;
    int orig = nbr[13 * (size_t)NV + r];
    int4 c = coords[orig];
    int k = 0;
    #pragma unroll
    for (int dz = -1; dz <= 1; dz++)
    #pragma unroll
    for (int dy = -1; dy <= 1; dy++)
    #pragma unroll
    for (int dx = -1; dx <= 1; dx++) {
        if (k != 13) {
            int z = c.y + dz, y = c.z + dy, x = c.w + dx;
            int idx = -1;
            if (z >= 0 && z < DD && y >= 0 && y < HH && x >= 0 && x < WW)
                idx = tab[((c.x * DD + z) * HH + y) * WW + x];
            nbr[(size_t)k * NV + r] = idx;
        }
        k++;
    }
}

// ---- layer 1 (rank space): one thread per sorted voxel ----
__global__ __launch_bounds__(256) void k_layer1(
        const float* __restrict__ feats_s, const int* __restrict__ nbr,
        const float* __restrict__ w1, const float* __restrict__ b1,
        const float* __restrict__ g1, const float* __restrict__ be1,
        const float* __restrict__ m1, const float* __restrict__ v1,
        f16* __restrict__ x1) {
    int i = blockIdx.x * 256 + threadIdx.x;   // i = rank
    bool act = (i < NV);
    int ii = act ? i : 0;

    float acc[CD];
    #pragma unroll
    for (int c = 0; c < CD; c++) acc[c] = 0.f;

    #pragma unroll
    for (int k = 0; k < KOFF; k++) {
        int idx = (k == 13) ? ii : (act ? nbr[(size_t)k * NV + ii] : -1);
        float fk = (idx >= 0) ? feats_s[idx] : 0.f;
        #pragma unroll
        for (int c = 0; c < CD; c++)
            acc[c] = fmaf(fk, w1[k * CD + c], acc[c]);
    }
    if (!act) return;

    #pragma unroll
    for (int c0 = 0; c0 < CD; c0 += 8) {
        f16x8 o;
        #pragma unroll
        for (int j = 0; j < 8; j++) {
            int c = c0 + j;
            float sc = g1[c] * rsqrtf(v1[c] + EPSV);
            float y = (acc[c] - m1[c] + b1[c]) * sc + be1[c];
            o[j] = (f16)fmaxf(y, 0.f);
        }
        *(f16x8*)(x1 + (size_t)i * CD + c0) = o;
    }
}

// ---- conv v15: v14 coop-gather + EXPLICIT LDS RAW FENCE.
// R9: v14 failed absmax 0.0996 (stale-data signature). Full algebraic audit
// cleared every mapping (bpermute lanes, window swizzle bijection, i1/i2
// rotation, VMW region-set counts). The one unprovable edge: same-wave
// ds_write A(K) -> ds_read A(K) RAW within a body relied on DS-pipe
// in-order processing. (The WAR direction IS provable: MFMA's lgkmcnt dep
// forces body K's reads to return before body K+1's writes issue.)
// Fix: s_waitcnt lgkmcnt(0) + sched_barrier(0) (rule #18) after the
// ds_writes, before each MFMA block. Cost ~0: writes are decades of cycles
// old there, and global_load_lds counts vmcnt only (ISA §7) so the B-staging
// pipeline is NOT drained by lgkmcnt(0) -- counted-vmcnt structure intact.
// Model unchanged (R4-calibrated TA line-request wall): coop gather cuts
// A-lines/wave/body 128 -> 32 (8 lanes load ONE contiguous 128B row; data
// to wave-private 4KB LDS window, XOR-swizzled slot^=(row&7); row indices
// via 4 ds_bpermute). Static vmem ops/body: 2 GLDS + 4 coop + 1 nbr.
//   body 0: WB=6 WM=4 | 1..24: WB=5 WM=3 | 25: WB=4 WM=2 | 26: WB=4 WM=0.
// k=13 (body 12 coop): self rows rs = rowb+8j+(l>>3), no bpermute.
#define MFMA3216(a, b, c) __builtin_amdgcn_mfma_f32_32x32x16_f16(a, b, c, 0, 0, 0)

#define VMW_(n) asm volatile("s_waitcnt vmcnt(" #n ")" ::: "memory")
#define VMW(n) VMW_(n)

#define CONV_BODY(K, WB, WM)                                                    \
  {                                                                             \
    VMW(WB);                                                                    \
    __builtin_amdgcn_s_barrier();                                               \
    asm volatile("" ::: "memory");                                              \
    if ((K) + 1 < KOFF) {                                                       \
      _Pragma("unroll")                                                         \
      for (int it = 0; it < 2; it++) {                                          \
        const char* gp = (const char*)wT + ((size_t)((K) + 1) * 8192            \
                          + it * 4096 + tid * 16);                              \
        char* lp = (char*)bbuf + (((K) + 1) & 1) * 8192 + it * 4096 + wv * 1024;\
        GLDS16(gp, lp);                                                         \
      }                                                                         \
    }                                                                           \
    asm volatile("" ::: "memory");                                              \
    VMW(WM);                                                                    \
    asm volatile("" ::: "memory");                                              \
    _Pragma("unroll")                                                           \
    for (int j = 0; j < 4; j++)                                                 \
      *(f16x8*)(aw + j * 1024 + wslot) = G[j];                                  \
    if ((K) + 1 < KOFF) {                                                       \
      _Pragma("unroll")                                                         \
      for (int j = 0; j < 4; j++) {                                             \
        int rs;                                                                 \
        if ((K) + 1 == 13) rs = rowb + j * 8 + (lane >> 3);                     \
        else rs = __builtin_amdgcn_ds_bpermute((j * 8 + (lane >> 3)) * 4, i1);  \
        const char* ap = ((rs >= 0)                                             \
            ? (const char*)xin + (size_t)rs * 128                               \
            : (const char*)zr) + (lane & 7) * 16;                               \
        G[j] = *(const f16x8*)ap;                                               \
      }                                                                         \
    }                                                                           \
    int iwN = i2;                                                               \
    if ((K) + 3 < KOFF)                                                         \
      iwN = nbr[(size_t)((K) + 3) * NV + row];                                  \
    asm volatile("" ::: "memory");                                              \
    asm volatile("s_waitcnt lgkmcnt(0)" ::: "memory");                          \
    __builtin_amdgcn_sched_barrier(0);                                          \
    __builtin_amdgcn_s_setprio(1);                                              \
    _Pragma("unroll")                                                           \
    for (int ks = 0; ks < 4; ks++) {                                            \
      const char* bp = (const char*)bbuf + ((K) & 1) * 8192                     \
                       + (2 * ks + g) * 1024;                                   \
      f16x8 b0 = *(const f16x8*)(bp + ml * 16);                                 \
      f16x8 b1 = *(const f16x8*)(bp + 512 + ml * 16);                           \
      f16x8 a = *(const f16x8*)(aw + ml * 128                                   \
                                + (((2 * ks + g) ^ (ml & 7)) * 16));            \
      acc[0] = MFMA3216(a, b0, acc[0]);                                         \
      acc[1] = MFMA3216(a, b1, acc[1]);                                         \
    }                                                                           \
    __builtin_amdgcn_s_setprio(0);                                              \
    i1 = i2; i2 = iwN;                                                          \
  }

static_assert(NV % 128 == 0, "grid must tile exactly");

template <bool OUTF32>
__global__ __launch_bounds__(256, 4) void k_conv(
        const f16* __restrict__ xin, const f16* __restrict__ wT,
        const int* __restrict__ nbr, const f16* __restrict__ zr,
        const float* __restrict__ bb, const float* __restrict__ gg,
        const float* __restrict__ bee, const float* __restrict__ mm,
        const float* __restrict__ vv, void* __restrict__ outp) {
    // 32 KB: B double-buffer [2][8192] + 4 wave-private A windows [4][4096].
    // First 16 KB doubles as the epilogue transpose scratch.
    __shared__ __align__(16) unsigned char smem[32768];
    unsigned char* bbuf = smem;
    unsigned char* sS = smem;

    const int tid = threadIdx.x;
    const int lane = tid & 63;
    const int wv = tid >> 6;
    const int g = lane >> 5;
    const int ml = lane & 31;
    // bijective XCD-chunked swizzle: grid 3125 = 8*390 + 5; first 5 XCDs get
    // 391 contiguous blocks, rest 390 -> each XCD walks its own rank window.
    int bid;
    {
        int x = blockIdx.x & 7, j = blockIdx.x >> 3;
        bid = (x < 5 ? x * 391 : 5 * 391 + (x - 5) * 390) + j;
    }
    const int vbase = bid * 128;
    const int rowb = vbase + wv * 32;         // wave's first voxel (rank space)
    const int row = rowb + ml;                // this lane's own voxel
    unsigned char* aw = smem + 16384 + wv * 4096;   // wave-private A window
    const int wslot = (lane >> 3) * 128 + ((lane & 7) ^ (lane >> 3)) * 16;

    f32x16 acc[2];
    #pragma unroll
    for (int b = 0; b < 2; b++) acc[b] = (f32x16)(0.f);

    f16x8 G[4];
    int i1, i2;

    // prologue: in0=idx(0); GLDS B(0); coop-load A(0)->G; i1=idx(1), i2=idx(2)
    int in0 = nbr[row];
    #pragma unroll
    for (int it = 0; it < 2; it++) {
        const char* gp = (const char*)wT + ((size_t)it * 4096 + tid * 16);
        char* lp = (char*)bbuf + it * 4096 + wv * 1024;
        GLDS16(gp, lp);
    }
    asm volatile("" ::: "memory");
    #pragma unroll
    for (int j = 0; j < 4; j++) {
        int rs = __builtin_amdgcn_ds_bpermute((j * 8 + (lane >> 3)) * 4, in0);
        const char* ap = ((rs >= 0)
            ? (const char*)xin + (size_t)rs * 128
            : (const char*)zr) + (lane & 7) * 16;
        G[j] = *(const f16x8*)ap;
    }
    i1 = nbr[(size_t)NV + row];
    i2 = nbr[2ull * NV + row];
    asm volatile("" ::: "memory");

    CONV_BODY(0, 6, 4)
    CONV_BODY(1, 5, 3)
    CONV_BODY(2, 5, 3)
    CONV_BODY(3, 5, 3)
    CONV_BODY(4, 5, 3)
    CONV_BODY(5, 5, 3)
    CONV_BODY(6, 5, 3)
    CONV_BODY(7, 5, 3)
    CONV_BODY(8, 5, 3)
    CONV_BODY(9, 5, 3)
    CONV_BODY(10, 5, 3)
    CONV_BODY(11, 5, 3)
    CONV_BODY(12, 5, 3)
    CONV_BODY(13, 5, 3)
    CONV_BODY(14, 5, 3)
    CONV_BODY(15, 5, 3)
    CONV_BODY(16, 5, 3)
    CONV_BODY(17, 5, 3)
    CONV_BODY(18, 5, 3)
    CONV_BODY(19, 5, 3)
    CONV_BODY(20, 5, 3)
    CONV_BODY(21, 5, 3)
    CONV_BODY(22, 5, 3)
    CONV_BODY(23, 5, 3)
    CONV_BODY(24, 5, 3)
    CONV_BODY(25, 4, 2)
    CONV_BODY(26, 4, 0)

    // epilogue: BN+ReLU -> LDS transpose -> vectorized stores
    if (!OUTF32) {
        __syncthreads();
        #pragma unroll
        for (int nt = 0; nt < 2; nt++) {
            int cn = nt * 32 + ml;
            float sc = gg[cn] * rsqrtf(vv[cn] + EPSV);
            float sh = (bb[cn] - mm[cn]) * sc + bee[cn];
            #pragma unroll
            for (int r = 0; r < 16; r++) {
                int rowl = wv * 32 + (r & 3) + 8 * (r >> 2) + 4 * g;
                float y = fmaxf(acc[nt][r] * sc + sh, 0.f);
                *(f16*)(sS + rowl * 128 + cn * 2) = (f16)y;
            }
        }
        __syncthreads();
        char* gb = (char*)outp + (size_t)vbase * 128;
        #pragma unroll
        for (int it = 0; it < 4; it++) {
            int s = it * 256 + tid;
            *(float4*)(gb + s * 16) = *(const float4*)(sS + s * 16);
        }
    } else {
        // scatter rows back to ORIGINAL voxel order via nbr[13] (orig index)
        #pragma unroll 1
        for (int p = 0; p < 2; p++) {
            __syncthreads();
            if ((wv >> 1) == p) {
                int lw = wv & 1;
                #pragma unroll
                for (int nt = 0; nt < 2; nt++) {
                    int cn = nt * 32 + ml;
                    float sc = gg[cn] * rsqrtf(vv[cn] + EPSV);
                    float sh = (bb[cn] - mm[cn]) * sc + bee[cn];
                    #pragma unroll
                    for (int r = 0; r < 16; r++) {
                        int rowl = lw * 32 + (r & 3) + 8 * (r >> 2) + 4 * g;
                        float y = fmaxf(acc[nt][r] * sc + sh, 0.f);
                        *(float*)(sS + rowl * 256 + cn * 4) = y;
                    }
                }
            }
            __syncthreads();
            #pragma unroll
            for (int it = 0; it < 4; it++) {
                int s = it * 256 + tid;
                int o = nbr[13 * (size_t)NV + vbase + p * 64 + (s >> 4)];
                *(float4*)((char*)outp + (size_t)o * 256 + (s & 15) * 16)
                    = *(const float4*)(sS + s * 16);
            }
        }
    }
}

extern "C" void kernel_launch(void* const* d_in, const int* in_sizes, int n_in,
                              void* d_out, int out_size, void* d_ws, size_t ws_size,
                              hipStream_t stream) {
    (void)in_sizes; (void)n_in; (void)out_size; (void)ws_size;
    const float* feats = (const float*)d_in[0];
    const int4* coords = (const int4*)d_in[1];
    const float* w1 = (const float*)d_in[2];
    const float* b1 = (const float*)d_in[3];
    const float* g1 = (const float*)d_in[4];
    const float* be1 = (const float*)d_in[5];
    const float* m1 = (const float*)d_in[6];
    const float* v1 = (const float*)d_in[7];
    const float* w2 = (const float*)d_in[8];
    const float* b2 = (const float*)d_in[9];
    const float* g2 = (const float*)d_in[10];
    const float* be2 = (const float*)d_in[11];
    const float* m2 = (const float*)d_in[12];
    const float* v2 = (const float*)d_in[13];
    const float* w3 = (const float*)d_in[14];
    const float* b3 = (const float*)d_in[15];
    const float* g3 = (const float*)d_in[16];
    const float* be3 = (const float*)d_in[17];
    const float* m3 = (const float*)d_in[18];
    const float* v3 = (const float*)d_in[19];

    char* ws = (char*)d_ws;
    int* nbr  = (int*)(ws + OFF_NBR);
    f16* x1   = (f16*)(ws + OFF_X1);
    f16* x2   = (f16*)(ws + OFF_X2);
    int* tab  = (int*)(ws + OFF_TAB);
    int* hist = (int*)(ws + OFF_HIST);
    float* fs = (float*)(ws + OFF_FS);
    f16* w2t  = (f16*)(ws + OFF_W2T);
    f16* w3t  = (f16*)(ws + OFF_W3T);
    f16* zrow = (f16*)(ws + OFF_ZERO);

    k_init<<<4096, 256, 0, stream>>>(w2, w3, tab, w2t, w3t, zrow, hist);
    k_hist<<<(NV + 255) / 256, 256, 0, stream>>>(coords, hist);
    k_scan<<<1, 1024, 0, stream>>>(hist);
    k_rank<<<(NV + 255) / 256, 256, 0, stream>>>(coords, feats, hist, tab, nbr, fs);
    k_nbr2<<<(NV + 255) / 256, 256, 0, stream>>>(coords, tab, nbr);
    k_layer1<<<(NV + 255) / 256, 256, 0, stream>>>(fs, nbr, w1, b1, g1, be1, m1, v1, x1);
    const int convgrid = NV / 128;  // 3125, exact
    k_conv<false><<<convgrid, 256, 0, stream>>>(x1, w2t, nbr, zrow, b2, g2, be2, m2, v2, (void*)x2);
    k_conv<true><<<convgrid, 256, 0, stream>>>(x2, w3t, nbr, zrow, b3, g3, be3, m3, v3, d_out);
}

// Round 11
// 490.927 us; speedup vs baseline: 1.1276x; 1.1276x over previous
//
#include <hip/hip_runtime.h>

#define NV 400000
#define KOFF 27
#define CD 64
#define DD 128
#define HH 128
#define WW 128
#define TABN (2*DD*HH*WW)
#define NCELL 32768
#define EPSV 1e-5f

typedef _Float16 f16;
typedef _Float16 f16x8 __attribute__((ext_vector_type(8)));
typedef float f32x16 __attribute__((ext_vector_type(16)));

// ---- workspace layout (bytes) ----
#define OFF_NBR   0ull
#define OFF_X1    43200000ull
#define OFF_X2    94400000ull
#define OFF_TAB   94400000ull     // table dead before x2 written
#define OFF_HIST  111177216ull    // 32K rows * 4B, inside x2 region (dead pre-conv2)
#define OFF_FS    111439360ull    // sorted feats, 1.6MB, inside x2 region (dead pre-conv2)
#define OFF_W2T   145600000ull
#define OFF_W3T   145821184ull
#define OFF_ZERO  146042368ull

#define GLDS16(gp, lp) __builtin_amdgcn_global_load_lds( \
    (__attribute__((address_space(1))) void*)(gp), \
    (__attribute__((address_space(3))) void*)(lp), 16, 0, 0)

// R10 fresh-eyes: prologue ~= 265us (> both convs), k_nbr's table reads the
// prime suspect (~4M random 128B line touches). 4^3 cells (9.5% density, ~6
// voxels) gave no line reuse -> R5 null. ROW-major buckets (b,z,y): ~12.2
// voxels/bucket share the SAME 9 neighbor-row line sets -> ~3 lines/voxel.
__device__ __forceinline__ int cell_of(int4 c) {
    return (c.x * DD + c.y) * HH + c.z;    // (b*128+z)*128+y, < 32768
}

// ---- init: table=-1; hist=0; weights -> f16 chunk-major wTg[k][cin/8][cout][cin&7]
__global__ void k_init(const float* __restrict__ w2, const float* __restrict__ w3,
                       int* __restrict__ tab, f16* __restrict__ w2t,
                       f16* __restrict__ w3t, f16* __restrict__ zrow,
                       int* __restrict__ hist) {
    int t = blockIdx.x * 256 + threadIdx.x;           // grid: 4096*256
    int4* tv = (int4*)tab;
    if (t < TABN / 4) tv[t] = make_int4(-1, -1, -1, -1);
    if (t < NCELL) hist[t] = 0;
    if (t < KOFF * CD * CD) {
        int k = t >> 12, r = t & 4095, c = r >> 6, ci = r & 63;
        int d = (k << 12) + ((ci >> 3) << 9) + (c << 3) + (ci & 7);
        w2t[d] = (f16)w2[(k << 12) + (ci << 6) + c];
        w3t[d] = (f16)w3[(k << 12) + (ci << 6) + c];
    }
    if (t < CD) zrow[t] = (f16)0.f;
}

// ---- spatial counting-sort: hist -> scan -> rank assignment ----
__global__ void k_hist(const int4* __restrict__ coords, int* __restrict__ hist) {
    int i = blockIdx.x * 256 + threadIdx.x;
    if (i >= NV) return;
    atomicAdd(&hist[cell_of(coords[i])], 1);
}

// exclusive prefix sum over 32768 ints, single workgroup of 1024 threads
__global__ __launch_bounds__(1024) void k_scan(int* __restrict__ hist) {
    __shared__ int part[1024];
    int t = threadIdx.x;
    int base = t * 32;
    int s = 0;
    #pragma unroll
    for (int j = 0; j < 32; j++) s += hist[base + j];
    part[t] = s;
    __syncthreads();
    for (int off = 1; off < 1024; off <<= 1) {
        int v = (t >= off) ? part[t - off] : 0;
        __syncthreads();
        part[t] += v;
        __syncthreads();
    }
    int ex = (t == 0) ? 0 : part[t - 1];
    #pragma unroll
    for (int j = 0; j < 32; j++) {
        int h = hist[base + j];
        hist[base + j] = ex;
        ex += h;
    }
}

// rank r = row-contiguous position. Writes:
//   tab[site] = r        (neighbor table in RANK space)
//   nbr[13*NV + r] = i   (k=13 is always self -> slot stores ORIG index:
//                         the scatter-back permutation, zero extra memory)
//   feats_s[r] = feats[i] (sorted features for layer 1)
__global__ void k_rank(const int4* __restrict__ coords, const float* __restrict__ feats,
                       int* __restrict__ hist, int* __restrict__ tab,
                       int* __restrict__ nbr, float* __restrict__ feats_s) {
    int i = blockIdx.x * 256 + threadIdx.x;
    if (i >= NV) return;
    int4 c = coords[i];
    int r = atomicAdd(&hist[cell_of(c)], 1);
    int flat = ((c.x * DD + c.y) * HH + c.z) * WW + c.w;
    tab[flat] = r;
    nbr[13 * (size_t)NV + r] = i;
    feats_s[r] = feats[i];
}

// neighbor rulebook in rank space; iterates SORTED (row-major) order so the
// ~12 voxels of one z-row reuse the same 9 neighbor-row line sets in L1.
// k=13 skipped (slot holds orig index).
__global__ void k_nbr2(const int4* __restrict__ coords, const int* __restrict__ tab,
                       int* __restrict__ nbr) {
    int r = blockIdx.x * 256 + threadIdx.x;
    if (r >= NV) return;
    int orig = nbr[13 * (size_t)NV + r];
    int4 c = coords[orig];
    int k = 0;
    #pragma unroll
    for (int dz = -1; dz <= 1; dz++)
    #pragma unroll
    for (int dy = -1; dy <= 1; dy++)
    #pragma unroll
    for (int dx = -1; dx <= 1; dx++) {
        if (k != 13) {
            int z = c.y + dz, y = c.z + dy, x = c.w + dx;
            int idx = -1;
            if (z >= 0 && z < DD && y >= 0 && y < HH && x >= 0 && x < WW)
                idx = tab[((c.x * DD + z) * HH + y) * WW + x];
            nbr[(size_t)k * NV + r] = idx;
        }
        k++;
    }
}

// ---- layer 1 (rank space): one thread per sorted voxel ----
__global__ __launch_bounds__(256) void k_layer1(
        const float* __restrict__ feats_s, const int* __restrict__ nbr,
        const float* __restrict__ w1, const float* __restrict__ b1,
        const float* __restrict__ g1, const float* __restrict__ be1,
        const float* __restrict__ m1, const float* __restrict__ v1,
        f16* __restrict__ x1) {
    int i = blockIdx.x * 256 + threadIdx.x;   // i = rank
    bool act = (i < NV);
    int ii = act ? i : 0;

    float acc[CD];
    #pragma unroll
    for (int c = 0; c < CD; c++) acc[c] = 0.f;

    #pragma unroll
    for (int k = 0; k < KOFF; k++) {
        int idx = (k == 13) ? ii : (act ? nbr[(size_t)k * NV + ii] : -1);
        float fk = (idx >= 0) ? feats_s[idx] : 0.f;
        #pragma unroll
        for (int c = 0; c < CD; c++)
            acc[c] = fmaf(fk, w1[k * CD + c], acc[c]);
    }
    if (!act) return;

    #pragma unroll
    for (int c0 = 0; c0 < CD; c0 += 8) {
        f16x8 o;
        #pragma unroll
        for (int j = 0; j < 8; j++) {
            int c = c0 + j;
            float sc = g1[c] * rsqrtf(v1[c] + EPSV);
            float y = (acc[c] - m1[c] + b1[c]) * sc + be1[c];
            o[j] = (f16)fmaxf(y, 0.f);
        }
        *(f16x8*)(x1 + (size_t)i * CD + c0) = o;
    }
}

// ---- conv v11 (verbatim from R5, proven 120.6us): v9 pipeline + rank-space.
// Seven structural variants (occupancy/barriers/drains/locality/depth/coop)
// all land ~118-145us -> conv treated as at its structural floor; this round
// targets the prologue instead. k=13: idx=row compile-time; nbr[13] carries
// orig index (scatter-back permutation). VMW analysis identical to v9:
// 2 GLDS + 4 A + 1 nbr per body; 6/5...5/4.
#define MFMA3216(a, b, c) __builtin_amdgcn_mfma_f32_32x32x16_f16(a, b, c, 0, 0, 0)

#define VMW_(n) asm volatile("s_waitcnt vmcnt(" #n ")" ::: "memory")
#define VMW(n) VMW_(n)

#define CONV_BODY(K, WN)                                                        \
  {                                                                             \
    VMW(WN);                                                                    \
    __builtin_amdgcn_s_barrier();                                               \
    asm volatile("" ::: "memory");                                              \
    if ((K) + 1 < KOFF) {                                                       \
      _Pragma("unroll")                                                         \
      for (int it = 0; it < 2; it++) {                                          \
        const char* gp = (const char*)wT + ((size_t)((K) + 1) * 8192            \
                          + it * 4096 + tid * 16);                              \
        char* lp = (char*)bbuf + (((K) + 1) & 1) * 8192 + it * 4096 + wv * 1024;\
        GLDS16(gp, lp);                                                         \
      }                                                                         \
      const int aidx = ((K) + 1 == 13) ? row : idxN;                            \
      const char* ap = ((aidx >= 0)                                             \
          ? (const char*)xin + (size_t)aidx * 128                               \
          : (const char*)zr) + g * 16;                                          \
      _Pragma("unroll")                                                         \
      for (int ks = 0; ks < 4; ks++)                                            \
        aF[((K) + 1) & 1][ks] = *(const f16x8*)(ap + ks * 32);                  \
    }                                                                           \
    int iwN = idxN;                                                             \
    if ((K) + 2 < KOFF)                                                         \
      iwN = nbr[(size_t)((K) + 2) * NV + row];                                  \
    asm volatile("" ::: "memory");                                              \
    __builtin_amdgcn_s_setprio(1);                                              \
    _Pragma("unroll")                                                           \
    for (int ks = 0; ks < 4; ks++) {                                            \
      const char* bp = (const char*)bbuf + ((K) & 1) * 8192                     \
                       + (2 * ks + g) * 1024;                                   \
      f16x8 b0 = *(const f16x8*)(bp + ml * 16);                                 \
      f16x8 b1 = *(const f16x8*)(bp + 512 + ml * 16);                           \
      acc[0] = MFMA3216(aF[(K) & 1][ks], b0, acc[0]);                           \
      acc[1] = MFMA3216(aF[(K) & 1][ks], b1, acc[1]);                           \
    }                                                                           \
    __builtin_amdgcn_s_setprio(0);                                              \
    idxN = iwN;                                                                 \
  }

static_assert(NV % 128 == 0, "grid must tile exactly");

template <bool OUTF32>
__global__ __launch_bounds__(256, 5) void k_conv(
        const f16* __restrict__ xin, const f16* __restrict__ wT,
        const int* __restrict__ nbr, const f16* __restrict__ zr,
        const float* __restrict__ bb, const float* __restrict__ gg,
        const float* __restrict__ bee, const float* __restrict__ mm,
        const float* __restrict__ vv, void* __restrict__ outp) {
    // 16 KB: B double-buffer [2][8192] during the loop; same bytes are the
    // epilogue transpose scratch after the last MFMA.
    __shared__ __align__(16) unsigned char smem[16384];
    unsigned char* bbuf = smem;
    unsigned char* sS = smem;

    const int tid = threadIdx.x;
    const int lane = tid & 63;
    const int wv = tid >> 6;
    const int g = lane >> 5;
    const int ml = lane & 31;
    // bijective XCD-chunked swizzle: grid 3125 = 8*390 + 5; first 5 XCDs get
    // 391 contiguous blocks, rest 390 -> each XCD walks its own rank window.
    int bid;
    {
        int x = blockIdx.x & 7, j = blockIdx.x >> 3;
        bid = (x < 5 ? x * 391 : 5 * 391 + (x - 5) * 390) + j;
    }
    const int vbase = bid * 128;
    const int row = vbase + wv * 32 + ml;     // this lane's A-row (rank space)

    f32x16 acc[2];
    #pragma unroll
    for (int b = 0; b < 2; b++) acc[b] = (f32x16)(0.f);

    f16x8 aF[2][4];
    int idxN;

    // prologue: stage B(0); fence; A(0) -> aF[0]; idx(1) -> idxN; fence
    #pragma unroll
    for (int it = 0; it < 2; it++) {
        const char* gp = (const char*)wT + ((size_t)it * 4096 + tid * 16);
        char* lp = (char*)bbuf + it * 4096 + wv * 1024;
        GLDS16(gp, lp);
    }
    asm volatile("" ::: "memory");
    {
        int iw0 = nbr[row];
        idxN = nbr[(size_t)NV + row];
        const char* ap = ((iw0 >= 0)
            ? (const char*)xin + (size_t)iw0 * 128
            : (const char*)zr) + g * 16;
        #pragma unroll
        for (int ks = 0; ks < 4; ks++)
            aF[0][ks] = *(const f16x8*)(ap + ks * 32);
    }
    asm volatile("" ::: "memory");

    CONV_BODY(0, 6)
    CONV_BODY(1, 5)
    CONV_BODY(2, 5)
    CONV_BODY(3, 5)
    CONV_BODY(4, 5)
    CONV_BODY(5, 5)
    CONV_BODY(6, 5)
    CONV_BODY(7, 5)
    CONV_BODY(8, 5)
    CONV_BODY(9, 5)
    CONV_BODY(10, 5)
    CONV_BODY(11, 5)
    CONV_BODY(12, 5)
    CONV_BODY(13, 5)
    CONV_BODY(14, 5)
    CONV_BODY(15, 5)
    CONV_BODY(16, 5)
    CONV_BODY(17, 5)
    CONV_BODY(18, 5)
    CONV_BODY(19, 5)
    CONV_BODY(20, 5)
    CONV_BODY(21, 5)
    CONV_BODY(22, 5)
    CONV_BODY(23, 5)
    CONV_BODY(24, 5)
    CONV_BODY(25, 5)
    CONV_BODY(26, 4)

    // epilogue: BN+ReLU -> LDS transpose -> vectorized stores
    if (!OUTF32) {
        __syncthreads();
        #pragma unroll
        for (int nt = 0; nt < 2; nt++) {
            int cn = nt * 32 + ml;
            float sc = gg[cn] * rsqrtf(vv[cn] + EPSV);
            float sh = (bb[cn] - mm[cn]) * sc + bee[cn];
            #pragma unroll
            for (int r = 0; r < 16; r++) {
                int rowl = wv * 32 + (r & 3) + 8 * (r >> 2) + 4 * g;
                float y = fmaxf(acc[nt][r] * sc + sh, 0.f);
                *(f16*)(sS + rowl * 128 + cn * 2) = (f16)y;
            }
        }
        __syncthreads();
        char* gb = (char*)outp + (size_t)vbase * 128;
        #pragma unroll
        for (int it = 0; it < 4; it++) {
            int s = it * 256 + tid;
            *(float4*)(gb + s * 16) = *(const float4*)(sS + s * 16);
        }
    } else {
        // scatter rows back to ORIGINAL voxel order via nbr[13] (orig index)
        #pragma unroll 1
        for (int p = 0; p < 2; p++) {
            __syncthreads();
            if ((wv >> 1) == p) {
                int lw = wv & 1;
                #pragma unroll
                for (int nt = 0; nt < 2; nt++) {
                    int cn = nt * 32 + ml;
                    float sc = gg[cn] * rsqrtf(vv[cn] + EPSV);
                    float sh = (bb[cn] - mm[cn]) * sc + bee[cn];
                    #pragma unroll
                    for (int r = 0; r < 16; r++) {
                        int rowl = lw * 32 + (r & 3) + 8 * (r >> 2) + 4 * g;
                        float y = fmaxf(acc[nt][r] * sc + sh, 0.f);
                        *(float*)(sS + rowl * 256 + cn * 4) = y;
                    }
                }
            }
            __syncthreads();
            #pragma unroll
            for (int it = 0; it < 4; it++) {
                int s = it * 256 + tid;
                int o = nbr[13 * (size_t)NV + vbase + p * 64 + (s >> 4)];
                *(float4*)((char*)outp + (size_t)o * 256 + (s & 15) * 16)
                    = *(const float4*)(sS + s * 16);
            }
        }
    }
}

extern "C" void kernel_launch(void* const* d_in, const int* in_sizes, int n_in,
                              void* d_out, int out_size, void* d_ws, size_t ws_size,
                              hipStream_t stream) {
    (void)in_sizes; (void)n_in; (void)out_size; (void)ws_size;
    const float* feats = (const float*)d_in[0];
    const int4* coords = (const int4*)d_in[1];
    const float* w1 = (const float*)d_in[2];
    const float* b1 = (const float*)d_in[3];
    const float* g1 = (const float*)d_in[4];
    const float* be1 = (const float*)d_in[5];
    const float* m1 = (const float*)d_in[6];
    const float* v1 = (const float*)d_in[7];
    const float* w2 = (const float*)d_in[8];
    const float* b2 = (const float*)d_in[9];
    const float* g2 = (const float*)d_in[10];
    const float* be2 = (const float*)d_in[11];
    const float* m2 = (const float*)d_in[12];
    const float* v2 = (const float*)d_in[13];
    const float* w3 = (const float*)d_in[14];
    const float* b3 = (const float*)d_in[15];
    const float* g3 = (const float*)d_in[16];
    const float* be3 = (const float*)d_in[17];
    const float* m3 = (const float*)d_in[18];
    const float* v3 = (const float*)d_in[19];

    char* ws = (char*)d_ws;
    int* nbr  = (int*)(ws + OFF_NBR);
    f16* x1   = (f16*)(ws + OFF_X1);
    f16* x2   = (f16*)(ws + OFF_X2);
    int* tab  = (int*)(ws + OFF_TAB);
    int* hist = (int*)(ws + OFF_HIST);
    float* fs = (float*)(ws + OFF_FS);
    f16* w2t  = (f16*)(ws + OFF_W2T);
    f16* w3t  = (f16*)(ws + OFF_W3T);
    f16* zrow = (f16*)(ws + OFF_ZERO);

    k_init<<<4096, 256, 0, stream>>>(w2, w3, tab, w2t, w3t, zrow, hist);
    k_hist<<<(NV + 255) / 256, 256, 0, stream>>>(coords, hist);
    k_scan<<<1, 1024, 0, stream>>>(hist);
    k_rank<<<(NV + 255) / 256, 256, 0, stream>>>(coords, feats, hist, tab, nbr, fs);
    k_nbr2<<<(NV + 255) / 256, 256, 0, stream>>>(coords, tab, nbr);
    k_layer1<<<(NV + 255) / 256, 256, 0, stream>>>(fs, nbr, w1, b1, g1, be1, m1, v1, x1);
    const int convgrid = NV / 128;  // 3125, exact
    k_conv<false><<<convgrid, 256, 0, stream>>>(x1, w2t, nbr, zrow, b2, g2, be2, m2, v2, (void*)x2);
    k_conv<true><<<convgrid, 256, 0, stream>>>(x2, w3t, nbr, zrow, b3, g3, be3, m3, v3, d_out);
}